// Round 1
// baseline (206.875 us; speedup 1.0000x reference)
//
#include <hip/hip_runtime.h>

// ---------------------------------------------------------------------------
// ANHPMultiHeadAttention: fused QKV projection + exp-scored causal attention
// B=8, S=1024, FEAT=HID=1024, H=8, DH=128.
//
// R6 changes vs R5:
//  - Evidence: gemm_qkv = 69.6us, MfmaUtil 31%, HBM 18%, conflicts 0 -> the
//    128^2 2-barrier structure's known ~740-900 TF ceiling (syncthreads
//    drains vmcnt(0) every K-step).
//  - GEMM rebuilt as the 256^2 8-phase schedule: one fused GEMM M=8192 x
//    N=3072 (W^T already n-major-contiguous across Q|K|V), 384 blocks x 512
//    threads (8 waves 2x4), BK=64, 128KB LDS 2-buf. Per tile: 4 phases
//    {ds_read subtile | stage 1 half-tile | bar | lgkm0 | setprio(1) 16 MFMA
//    setprio(0) | bar}; counted s_waitcnt vmcnt(4) once per K-tile (never 0
//    in steady state; vmcnt(0) only at tile NT-2). Raw s_barrier + memory
//    fences keep global_load_lds prefetches in flight across barriers.
//    Stage/readback schedule re-derived so a region is only staged >=1 full
//    phase after its last ds_read (A buf free after P3, B buf free after P2).
//  - prep / attn unchanged (verified).
// ---------------------------------------------------------------------------

typedef __bf16 bf16x8 __attribute__((ext_vector_type(8)));
typedef float floatx4 __attribute__((ext_vector_type(4)));
typedef unsigned short u16;
typedef unsigned int u32;

#define RSCALE 0.08838834764831845f   // 1/sqrt(128)

__device__ __forceinline__ u16 f2b(float f) {       // fp32 -> bf16 bits, RNE
  union { float f; unsigned u; } v; v.f = f;
  return (u16)((v.u + 0x7FFFu + ((v.u >> 16) & 1u)) >> 16);
}

// async global->LDS, 16B per lane. LDS dst = wave-uniform base + lane*16.
__device__ __forceinline__ void gld_lds16(const void* g, void* l) {
  __builtin_amdgcn_global_load_lds(
      (const __attribute__((address_space(1))) unsigned*)g,
      (__attribute__((address_space(3))) unsigned*)l, 16, 0, 0);
}

#define MFMA16(a, b, c) __builtin_amdgcn_mfma_f32_16x16x32_bf16(a, b, c, 0, 0, 0)

// Raw barrier with compiler-level memory fences on both sides: LDS/global ops
// cannot be moved across it, but it does NOT drain vmcnt (unlike syncthreads).
__device__ __forceinline__ void barrier_mem() {
  asm volatile("" ::: "memory");
  __builtin_amdgcn_s_barrier();
  asm volatile("" ::: "memory");
}
#define WAIT_LGKM0() asm volatile("s_waitcnt lgkmcnt(0)" ::: "memory")
#define WAIT_VM4()   asm volatile("s_waitcnt vmcnt(4)" ::: "memory")
#define WAIT_VM0()   asm volatile("s_waitcnt vmcnt(0)" ::: "memory")

// ---------------------------------------------------------------------------
// Kernel 1: prep = cast X (blocks 0..8191) + transpose W (blocks 8192..11263)
// ---------------------------------------------------------------------------
__global__ __launch_bounds__(256) void prep_kernel(
    const float4* __restrict__ X, u16* __restrict__ Xb,
    const float* __restrict__ Wq, const float* __restrict__ Wk,
    const float* __restrict__ Wv, u16* __restrict__ Wtb) {
  if (blockIdx.x < 8192) {
    unsigned i = blockIdx.x * 256u + threadIdx.x;
    float4 v = X[i];
    ushort4 o;
    o.x = f2b(v.x); o.y = f2b(v.y); o.z = f2b(v.z); o.w = f2b(v.w);
    *reinterpret_cast<ushort4*>(Xb + 4u * i) = o;
  } else {
    const int bid = blockIdx.x - 8192;          // 0..3071
    const int mat = bid >> 10;                  // 1024 blocks per matrix
    const int bx = bid & 31, by = (bid >> 5) & 31;
    const float* W = (mat == 0) ? Wq : (mat == 1) ? Wk : Wv;
    u16* Wt = Wtb + (size_t)mat * (1024u * 1024u);
    __shared__ u16 tile[32][33];
    const int x = threadIdx.x & 31, y = threadIdx.x >> 5;
    const int kt = bx * 32, nt = by * 32;
#pragma unroll
    for (int i = 0; i < 4; ++i)
      tile[y + 8 * i][x] = f2b(W[(size_t)(kt + y + 8 * i) * 1024 + nt + x]);
    __syncthreads();
#pragma unroll
    for (int i = 0; i < 4; ++i)
      Wt[(size_t)(nt + y + 8 * i) * 1024 + kt + x] = tile[x][y + 8 * i];
  }
}

// ---------------------------------------------------------------------------
// Kernel 2: fused QKV GEMM, 256x256 tile, BK=64, 8-phase counted-vmcnt
// schedule. M=8192, N=3072 (Q|K|V n-panels of W^T are contiguous). Grid 384,
// block 512 (8 waves, 2m x 4n, each wave 128x64 out = acc[8][4]).
// LDS: A,B each 2 x 256x64 bf16 (32KB/buf) = 128KB -> 1 block/CU.
// Per K-tile t (phases P1..P4, per wave):
//   P1: ds A-m0(8)+B-n0(4); stage A(t+1)h0; MFMA acc[0:4][0:2]
//   P2: ds B-n1(4);         stage A(t+1)h1; MFMA acc[0:4][2:4]
//   P3: ds A-m1(8);         stage B(t+2)h0; MFMA acc[4:8][2:4]
//   P4: (reg reuse only);   stage B(t+2)h1; MFMA acc[4:8][0:2]; vmcnt(4)
// Safety: A(t) last ds_read at P3(t) -> A(t+2) staged P1/P2(t+1) OK.
//         B(t) last ds_read at P2(t) -> B(t+2) staged P3/P4(t) OK.
// vmcnt(4) at end-P4 forces A(t+1),B(t+1) landed (4 newer calls = B(t+2))
// before every wave's trailing barrier; P1(t+1) ds_reads follow the barrier.
// Tail: vmcnt(0) at t=NT-2 (no newer loads exist to count against).
// Q,K stored [B,H,S,DH]; V stored [B,H,DH,S] (transposed).
// ---------------------------------------------------------------------------
__global__ __launch_bounds__(512, 2) void gemm_qkv_kernel(
    const u16* __restrict__ Xb, const u16* __restrict__ Wtb,
    const float* __restrict__ bq, const float* __restrict__ bk,
    const float* __restrict__ bv, u16* __restrict__ Qh, u16* __restrict__ Kh,
    u16* __restrict__ Vt) {
  // XCD-chunked swizzle: 384 blocks = 8 XCDs x 48. Within an XCD: n fastest
  // -> 4 m-panels (4x512KB=2MB) reused across all 12 n-tiles from XCD L2.
  const int id = blockIdx.x;
  const int swz = (id & 7) * 48 + (id >> 3);
  const int m0 = (swz / 12) * 256;
  const int n0g = (swz % 12) * 256;           // global n in [0,3072)

  __shared__ u16 As[2][256 * 64];   // [m][k], 128B rows
  __shared__ u16 Bs[2][256 * 64];   // [n][k]

  const int tid = threadIdx.x;
  const int wid = tid >> 6;
  const int lane = tid & 63;
  const int quad = lane >> 4;
  const int l16 = lane & 15;
  const int swzr = l16 & 7;                   // read-side xor8 (row&7)
  const int wrm = (wid >> 2) * 128;           // wave m offset: 0/128
  const int wcn = (wid & 3) * 64;             // wave n offset: 0..192

  // staging: one call = 512 lanes x 16B = 64 rows; LDS linear, source xor8.
  const int srow = tid >> 3;                  // 0..63
  const int sunit = (tid & 7) ^ (srow & 7);

  auto stageA = [&](int buf, int h, int kk) {
#pragma unroll
    for (int c = 0; c < 2; ++c)
      gld_lds16(
          Xb + (size_t)(m0 + h * 128 + c * 64 + srow) * 1024 + kk + sunit * 8,
          &As[buf][(h * 128 + c * 64 + wid * 8) * 64]);
  };
  auto stageB = [&](int buf, int h, int kk) {
#pragma unroll
    for (int c = 0; c < 2; ++c)
      gld_lds16(
          Wtb + (size_t)(n0g + h * 128 + c * 64 + srow) * 1024 + kk + sunit * 8,
          &Bs[buf][(h * 128 + c * 64 + wid * 8) * 64]);
  };

  const floatx4 z4 = {0.f, 0.f, 0.f, 0.f};
  floatx4 acc[8][4];
#pragma unroll
  for (int i = 0; i < 8; ++i)
#pragma unroll
    for (int j = 0; j < 4; ++j) acc[i][j] = z4;

  bf16x8 aR[4][2];   // current m-sub A frags
  bf16x8 bA[2][2];   // B n-sub0 frags (live P1..P4)
  bf16x8 bB[2][2];   // B n-sub1 frags (live P2..P3)

  // prologue: A(0), B(0), B(1) = 12 calls; vmcnt(4) leaves B(1) in flight.
  stageA(0, 0, 0); stageA(0, 1, 0);
  stageB(0, 0, 0); stageB(0, 1, 0);
  stageB(1, 0, 64); stageB(1, 1, 64);
  WAIT_VM4();
  barrier_mem();

#pragma unroll 1
  for (int t = 0; t < 16; ++t) {
    const u16* __restrict__ Ab = As[t & 1];
    const u16* __restrict__ Bb = Bs[t & 1];
    const int nb = (t + 1) & 1;

    // ---- P1: ds A-m0 + B-n0; stage A(t+1)h0; MFMA acc[0:4][0:2]
#pragma unroll
    for (int i = 0; i < 4; ++i)
#pragma unroll
      for (int c = 0; c < 2; ++c)
        aR[i][c] = *(const bf16x8*)(Ab + (wrm + i * 16 + l16) * 64 +
                                    (((c * 4 + quad) ^ swzr) * 8));
#pragma unroll
    for (int j = 0; j < 2; ++j)
#pragma unroll
      for (int c = 0; c < 2; ++c)
        bA[j][c] = *(const bf16x8*)(Bb + (wcn + j * 16 + l16) * 64 +
                                    (((c * 4 + quad) ^ swzr) * 8));
    if (t < 15) stageA(nb, 0, (t + 1) * 64);
    barrier_mem();
    WAIT_LGKM0();
    __builtin_amdgcn_s_setprio(1);
#pragma unroll
    for (int c = 0; c < 2; ++c)
#pragma unroll
      for (int i = 0; i < 4; ++i)
#pragma unroll
        for (int j = 0; j < 2; ++j)
          acc[i][j] = MFMA16(aR[i][c], bA[j][c], acc[i][j]);
    __builtin_amdgcn_s_setprio(0);
    barrier_mem();

    // ---- P2: ds B-n1; stage A(t+1)h1; MFMA acc[0:4][2:4]
#pragma unroll
    for (int j = 0; j < 2; ++j)
#pragma unroll
      for (int c = 0; c < 2; ++c)
        bB[j][c] = *(const bf16x8*)(Bb + (wcn + 32 + j * 16 + l16) * 64 +
                                    (((c * 4 + quad) ^ swzr) * 8));
    if (t < 15) stageA(nb, 1, (t + 1) * 64);
    barrier_mem();
    WAIT_LGKM0();
    __builtin_amdgcn_s_setprio(1);
#pragma unroll
    for (int c = 0; c < 2; ++c)
#pragma unroll
      for (int i = 0; i < 4; ++i)
#pragma unroll
        for (int j = 0; j < 2; ++j)
          acc[i][2 + j] = MFMA16(aR[i][c], bB[j][c], acc[i][2 + j]);
    __builtin_amdgcn_s_setprio(0);
    barrier_mem();

    // ---- P3: ds A-m1; stage B(t+2)h0; MFMA acc[4:8][2:4]
#pragma unroll
    for (int i = 0; i < 4; ++i)
#pragma unroll
      for (int c = 0; c < 2; ++c)
        aR[i][c] = *(const bf16x8*)(Ab + (wrm + 64 + i * 16 + l16) * 64 +
                                    (((c * 4 + quad) ^ swzr) * 8));
    if (t < 14) stageB(t & 1, 0, (t + 2) * 64);
    barrier_mem();
    WAIT_LGKM0();
    __builtin_amdgcn_s_setprio(1);
#pragma unroll
    for (int c = 0; c < 2; ++c)
#pragma unroll
      for (int i = 0; i < 4; ++i)
#pragma unroll
        for (int j = 0; j < 2; ++j)
          acc[4 + i][2 + j] = MFMA16(aR[i][c], bB[j][c], acc[4 + i][2 + j]);
    __builtin_amdgcn_s_setprio(0);
    barrier_mem();

    // ---- P4: reg reuse only; stage B(t+2)h1; MFMA acc[4:8][0:2]; gate.
    if (t < 14) stageB(t & 1, 1, (t + 2) * 64);
    barrier_mem();
    WAIT_LGKM0();
    __builtin_amdgcn_s_setprio(1);
#pragma unroll
    for (int c = 0; c < 2; ++c)
#pragma unroll
      for (int i = 0; i < 4; ++i)
#pragma unroll
        for (int j = 0; j < 2; ++j)
          acc[4 + i][j] = MFMA16(aR[i][c], bA[j][c], acc[4 + i][j]);
    __builtin_amdgcn_s_setprio(0);
    if (t < 14) { WAIT_VM4(); }
    else if (t == 14) { WAIT_VM0(); }
    barrier_mem();
  }

  // epilogue. C/D layout: col = l16 (n), row = quad*4 + reg (m).
  const int mat = n0g >> 10;                  // 0:Q 1:K 2:V (no straddle)
  const int nn = n0g & 1023;
  const float* __restrict__ bias = (mat == 0) ? bq : (mat == 1) ? bk : bv;
  const int b = m0 >> 10;
  const int sbase = (m0 & 1023) + wrm;
  float bias4[4];
#pragma unroll
  for (int j = 0; j < 4; ++j) bias4[j] = bias[nn + wcn + j * 16 + l16];

  if (mat < 2) {
    u16* outp = (mat == 0 ? Qh : Kh) + (size_t)b * 8 * 1024 * 128;
#pragma unroll
    for (int fi = 0; fi < 8; ++fi)
#pragma unroll
      for (int j = 0; j < 4; ++j) {
        const int dg = nn + wcn + j * 16 + l16;   // 0..1023
        const int h = dg >> 7, d = dg & 127;
        const int s = sbase + fi * 16 + quad * 4;
        u16* p = outp + (size_t)h * 1024 * 128 + (size_t)s * 128 + d;
#pragma unroll
        for (int r = 0; r < 4; ++r)
          p[(size_t)r * 128] = f2b(acc[fi][j][r] + bias4[j]);
      }
  } else {
    // V^T: out[((b*8+h)*128 + d)*1024 + s]; 4 regs = 4 consecutive s.
    u16* outp = Vt + (size_t)b * 8 * 128 * 1024;
#pragma unroll
    for (int fi = 0; fi < 8; ++fi)
#pragma unroll
      for (int j = 0; j < 4; ++j) {
        const int dg = nn + wcn + j * 16 + l16;
        const int h = dg >> 7, d = dg & 127;
        const int s = sbase + fi * 16 + quad * 4;
        ushort4 pk;
        pk.x = f2b(acc[fi][j][0] + bias4[j]);
        pk.y = f2b(acc[fi][j][1] + bias4[j]);
        pk.z = f2b(acc[fi][j][2] + bias4[j]);
        pk.w = f2b(acc[fi][j][3] + bias4[j]);
        *(ushort4*)(outp + (size_t)h * 128 * 1024 + (size_t)d * 1024 + s) = pk;
      }
  }
}

// ---------------------------------------------------------------------------
// Kernel 3: attention. grid 512 (all co-resident: 2 blocks/CU), block 256
// (4 waves x 32 q-rows, BQ=128). BK=64, K+V double-buffered, ONE barrier per
// iteration. XCD pinning: xcd = id&7 owns bh in [8*xcd, 8*xcd+8) -> K+V
// working set 4MB = one XCD L2; q-tiles share it. qt pairing balances CUs.
// S^T = MFMA(kf,qf); PV in two 32-key half-chunks via 2KB/wave Ps;
// O^T = MFMA(vf,pa) -> float4 stores.
// ---------------------------------------------------------------------------
__global__ __launch_bounds__(256, 2) void attn_kernel(const u16* __restrict__ Qh,
                                                      const u16* __restrict__ Kh,
                                                      const u16* __restrict__ Vt,
                                                      float* __restrict__ out) {
  const int id = blockIdx.x;
  const int x = id & 7;               // XCD (blocks round-robin by id%8)
  const int j = id >> 3;              // 0..63 within XCD
  const int bh = x * 8 + (j & 7);     // 8 heads pinned per XCD
  // CU-paired qt schedule: pairs (7,0),(5,2),(6,1),(4,3) -> equal work/CU.
  const int QTMAP[8] = {7, 5, 6, 4, 0, 2, 1, 3};
  const int qt = QTMAP[j >> 3];
  const int q0 = qt * 128;

  const int tid = threadIdx.x;
  const int wid = tid >> 6;
  const int lane = tid & 63;
  const int quad = lane >> 4;
  const int l16 = lane & 15;

  __shared__ u16 Ks[2][64 * 128];   // [key][d] 256B rows, 16KB each
  __shared__ u16 Vs[2][128 * 64];   // [d][key] 128B rows, 16KB each
  __shared__ u16 Ps[4][32 * 32];    // per-wave [q][32-key half] 64B rows, 2KB

  const u16* __restrict__ Qbase = Qh + (size_t)bh * 1024 * 128;
  const u16* __restrict__ Kbase = Kh + (size_t)bh * 1024 * 128;
  const u16* __restrict__ Vbase = Vt + (size_t)bh * 128 * 1024;

  const int qw = q0 + wid * 32;     // this wave's 32 q-rows

  // Q B-frags (for S^T = MFMA(kf,qf)): lane l16 = q, k = quad*8+j.
  bf16x8 qf[2][4];
#pragma unroll
  for (int nt = 0; nt < 2; ++nt)
#pragma unroll
    for (int c = 0; c < 4; ++c)
      qf[nt][c] = *(const bf16x8*)(Qbase + (size_t)(qw + nt * 16 + l16) * 128 +
                                   c * 32 + quad * 8);

  const floatx4 z4 = {0.f, 0.f, 0.f, 0.f};
  floatx4 o[2][8];
#pragma unroll
  for (int nt = 0; nt < 2; ++nt)
#pragma unroll
    for (int dt = 0; dt < 8; ++dt) o[nt][dt] = z4;
  float lacc[2] = {0.f, 0.f};

  // staging: K 64 rows x 256B (wave: 16 rows, 4 rows/call);
  //          V 128 rows x 128B (wave: 32 rows, 8 rows/call).
  auto stage = [&](int b, int k0) {
#pragma unroll
    for (int c = 0; c < 4; ++c) {
      const int r0 = wid * 16 + c * 4;
      const int row = r0 + quad;                       // row & 15 = c*4+quad
      gld_lds16(Kbase + (size_t)(k0 + row) * 128 + ((l16 ^ (c * 4 + quad)) * 8),
                Ks[b] + r0 * 128);
    }
#pragma unroll
    for (int c = 0; c < 4; ++c) {
      const int r0 = wid * 32 + c * 8;
      const int row = r0 + (lane >> 3);                // row & 7 = lane>>3 &7
      gld_lds16(Vbase + (size_t)row * 1024 + k0 +
                    (((lane & 7) ^ ((lane >> 3) & 7)) * 8),
                Vs[b] + r0 * 64);
    }
  };

  const int n = (q0 + 128) >> 6;    // 64-key iterations: 2..16
  stage(0, 0);

  for (int i = 0; i < n; ++i) {
    const int k0 = i << 6;
    __syncthreads();                // drains prefetch(i); frees buf (i-1)&1
    if (i + 1 < n) stage((i + 1) & 1, k0 + 64);

    const u16* __restrict__ Kb = Ks[i & 1];
    const u16* __restrict__ Vb = Vs[i & 1];

#pragma unroll
    for (int half = 0; half < 2; ++half) {
      if (k0 + half * 32 > qw + 31) break;   // wave-uniform causal skip

      // QK for the half's two 16-key tiles; write P into Ps.
#pragma unroll
      for (int f2 = 0; f2 < 2; ++f2) {
        const int f = half * 2 + f2;
        bf16x8 kf[4];
#pragma unroll
        for (int c = 0; c < 4; ++c)
          kf[c] = *(const bf16x8*)(Kb + (f * 16 + l16) * 128 +
                                   (((c * 4 + quad) ^ l16) * 8));
        floatx4 st[2];
#pragma unroll
        for (int nt = 0; nt < 2; ++nt) {
          st[nt] = z4;
#pragma unroll
          for (int c = 0; c < 4; ++c) st[nt] = MFMA16(kf[c], qf[nt][c], st[nt]);
        }
        const int kb = k0 + f * 16 + quad * 4;
#pragma unroll
        for (int nt = 0; nt < 2; ++nt) {
          const int qrow = qw + nt * 16 + l16;
          float p[4];
#pragma unroll
          for (int r = 0; r < 4; ++r) {
            const float e = fminf(__expf(st[nt][r] * RSCALE), 85.f);
            p[r] = (kb + r > qrow) ? 0.f : __expf(e);
          }
          lacc[nt] += (p[0] + p[1]) + (p[2] + p[3]);
          uint2 pk;
          pk.x = (u32)f2b(p[0]) | ((u32)f2b(p[1]) << 16);
          pk.y = (u32)f2b(p[2]) | ((u32)f2b(p[3]) << 16);
          // Ps row = nt*16+l16 (64B); 16B unit u = f2*2+(quad>>1), sub=quad&1;
          // unit-swizzle u ^= (l16&3).
          *(uint2*)((char*)Ps[wid] + (nt * 16 + l16) * 64 +
                    (((f2 * 2 + (quad >> 1)) ^ (l16 & 3)) * 16) +
                    (quad & 1) * 8) = pk;
        }
      }
      asm volatile("s_waitcnt lgkmcnt(0)" ::: "memory");  // own P visible

      // PV for this 32-key half. pa: B[k=key][n=q], lane l16=q, unit=quad^s.
      bf16x8 pa[2];
#pragma unroll
      for (int nt = 0; nt < 2; ++nt)
        pa[nt] = *(const bf16x8*)((char*)Ps[wid] + (nt * 16 + l16) * 64 +
                                  ((quad ^ (l16 & 3)) * 16));
#pragma unroll
      for (int dt = 0; dt < 8; ++dt) {
        const bf16x8 vf = *(const bf16x8*)(
            Vb + (dt * 16 + l16) * 64 +
            (((half * 4 + quad) ^ (l16 & 7)) * 8));
        o[0][dt] = MFMA16(vf, pa[0], o[0][dt]);
        o[1][dt] = MFMA16(vf, pa[1], o[1][dt]);
      }
    }
  }

  // l reduce across quads (lanes sharing l16), normalize, store.
  float linv[2];
#pragma unroll
  for (int nt = 0; nt < 2; ++nt) {
    float s = lacc[nt];
    s += __shfl_xor(s, 16);
    s += __shfl_xor(s, 32);
    linv[nt] = 1.0f / s;
  }

  // O^T C-layout: col(l16)=q, row(quad*4+r)=d -> contiguous float4.
  float* outp = out + (size_t)(bh >> 3) * 1024 * 1024 + (bh & 7) * 128;
#pragma unroll
  for (int nt = 0; nt < 2; ++nt) {
    const int qrow = qw + nt * 16 + l16;
#pragma unroll
    for (int dt = 0; dt < 8; ++dt) {
      float4 v;
      v.x = o[nt][dt][0] * linv[nt];
      v.y = o[nt][dt][1] * linv[nt];
      v.z = o[nt][dt][2] * linv[nt];
      v.w = o[nt][dt][3] * linv[nt];
      *(float4*)(outp + (size_t)qrow * 1024 + dt * 16 + quad * 4) = v;
    }
  }
}

// ---------------------------------------------------------------------------
extern "C" void kernel_launch(void* const* d_in, const int* in_sizes, int n_in,
                              void* d_out, int out_size, void* d_ws,
                              size_t ws_size, hipStream_t stream) {
  const float* X = (const float*)d_in[0];
  const float* Wq = (const float*)d_in[1];
  const float* bq = (const float*)d_in[2];
  const float* Wk = (const float*)d_in[3];
  const float* bk = (const float*)d_in[4];
  const float* Wv = (const float*)d_in[5];
  const float* bv = (const float*)d_in[6];
  float* out = (float*)d_out;

  char* ws = (char*)d_ws;
  u16* Xb  = (u16*)(ws);                         // 16 MB  bf16 X
  u16* Wtb = (u16*)(ws + (16u << 20));           //  6 MB  bf16 W^T x3
  u16* Qh  = (u16*)(ws + (22u << 20));           // 16 MB  [B,H,S,DH]
  u16* Kh  = (u16*)(ws + (38u << 20));           // 16 MB  [B,H,S,DH]
  u16* Vt  = (u16*)(ws + (54u << 20));           // 16 MB  [B,H,DH,S]

  prep_kernel<<<8192 + 3072, 256, 0, stream>>>((const float4*)X, Xb, Wq, Wk,
                                               Wv, Wtb);
  gemm_qkv_kernel<<<384, 512, 0, stream>>>(Xb, Wtb, bq, bk, bv, Qh, Kh, Vt);
  attn_kernel<<<512, 256, 0, stream>>>(Qh, Kh, Vt, out);
}